// Round 8
// baseline (152.191 us; speedup 1.0000x reference)
//
#include <hip/hip_runtime.h>

#define NE 32   // electrons
#define NA 8    // atoms
#define DF 4    // dist features
#define KD 8    // kernel dim
#define ED 16   // embedding dim
#define BATCH 4096

// d_ws layout (floats) — all offsets even (f32x2-aligned)
#define WS_W1S0 0     // w1[n=0]*log2e   (d*6+a), 24
#define WS_W1S1 24
#define WS_B1S0 48    // wb1*log2e, 6 each
#define WS_B1S1 54
#define WS_B2H0 60    // wb2*log2e - sum_a w2[a][k], 8 each
#define WS_B2H1 68
#define WS_MS0  76    // n=0 same-spin msg vector, 8
#define WS_MA0  84    // n=0 anti-spin msg vector, 8
#define WS_MS   92    // Ms[kp][k] = (ln2*g_w0) @ hs_w1, 8x8
#define WS_MA   156   // Ma[kp][k] = (ln2*g_w0) @ ha_w1, 8x8
#define WS_CS   220   // (X+g_b0)@hs_w1 + hs_b1, 8
#define WS_CA   228
#define WS_GO0  236   // ln2*g_w0 @ orb, 8
#define WS_GO1  244
#define WS_BASE 252   // (X+g_b0+g_b1)@orb, 1

typedef float f32x2 __attribute__((ext_vector_type(2)));
__device__ __forceinline__ f32x2 splat2(float s) { f32x2 r; r.x = s; r.y = s; return r; }
__device__ __forceinline__ f32x2 fma2(f32x2 a, f32x2 b, f32x2 c) {
    return __builtin_elementwise_fma(a, b, c);
}

__global__ void omni_setup(const float* __restrict__ X,   const float* __restrict__ w1,
                           const float* __restrict__ wb1, const float* __restrict__ w2,
                           const float* __restrict__ wb2, const float* __restrict__ hs_w,
                           const float* __restrict__ hs_b,const float* __restrict__ ha_w,
                           const float* __restrict__ ha_b,const float* __restrict__ g_w,
                           const float* __restrict__ g_b, const float* __restrict__ orb_w,
                           float* __restrict__ ws)
{
    const int t = threadIdx.x;
    const float L   = 1.4426950408889634f;   // log2(e)
    const float LN2 = 0.6931471805599453f;
    if (t < 48) {                                   // W1s, both n
        ws[t] = w1[t] * L;
    } else if (t < 60) {                            // B1s
        ws[t] = wb1[t - 48] * L;
    } else if (t < 76) {                            // B2h
        const int u = t - 60, n = u >> 3, k = u & 7;
        float sw = 0.f;
        for (int a = 0; a < 6; ++a) sw += w2[n * 48 + a * KD + k];
        ws[t] = wb2[n * KD + k] * L - sw;
    } else if (t < 92) {                            // ms0 / ma0
        const int u = t - 76, tab = u >> 3, k = u & 7;
        const float* mw = tab ? ha_w : hs_w;        // n=0 slice
        const float* mb = tab ? ha_b : hs_b;
        float acc = mb[k];
        for (int c = 0; c < ED; ++c) acc += X[c] * mw[c * KD + k];
        ws[t] = acc;
    } else if (t < 220) {                           // Ms / Ma (8x8)
        int u = t - 92; const int tab = u >> 6; u &= 63;
        const int kp = u >> 3, k = u & 7;
        const float* mw = (tab ? ha_w : hs_w) + ED * KD;   // n=1 slice
        float acc = 0.f;
        for (int c = 0; c < ED; ++c)
            acc += LN2 * g_w[kp * ED + c] * mw[c * KD + k]; // g_w n=0 slice
        ws[t] = acc;
    } else if (t < 236) {                           // Cs / Ca
        const int u = t - 220, tab = u >> 3, k = u & 7;
        const float* mw = (tab ? ha_w : hs_w) + ED * KD;
        const float* mb = (tab ? ha_b : hs_b) + KD;
        float acc = mb[k];
        for (int c = 0; c < ED; ++c) acc += (X[c] + g_b[c]) * mw[c * KD + k];
        ws[t] = acc;
    } else if (t < 252) {                           // go0 / go1
        const int u = t - 236, n = u >> 3, k = u & 7;
        float acc = 0.f;
        for (int c = 0; c < ED; ++c)
            acc += LN2 * g_w[n * KD * ED + k * ED + c] * orb_w[c];
        ws[t] = acc;
    } else if (t == 252) {                          // base
        float acc = 0.f;
        for (int c = 0; c < ED; ++c) acc += (X[c] + g_b[c] + g_b[ED + c]) * orb_w[c];
        ws[t] = acc;
    }
}

// trans stage, k-packed: r2[a2] = log2(1 + 2^(e@W1s + B1s)) for unit pair a2
__device__ __forceinline__ void wnet_r2(const float4 e,
                                        const f32x2* __restrict__ vB1s2,  // 3
                                        const f32x2* __restrict__ sW12,   // 12: d*3+a2
                                        f32x2* __restrict__ r2)           // 3
{
    #pragma unroll
    for (int a2 = 0; a2 < 3; ++a2) {
        f32x2 u = fma2(splat2(e.x), sW12[a2], vB1s2[a2]);
        u = fma2(splat2(e.y), sW12[3 + a2], u);
        u = fma2(splat2(e.z), sW12[6 + a2], u);
        u = fma2(splat2(e.w), sW12[9 + a2], u);
        f32x2 t;
        t.x = __builtin_amdgcn_exp2f(u.x);
        t.y = __builtin_amdgcn_exp2f(u.y);
        t = t + splat2(1.0f);
        r2[a2].x = __builtin_amdgcn_logf(t.x);
        r2[a2].y = __builtin_amdgcn_logf(t.y);
    }
}

// projection, k-packed: racc2[k2] = B2h2[k2] + sum_a r[a]*W2[a][k-pair]
__device__ __forceinline__ void proj2(const f32x2* __restrict__ r2,
                                      const f32x2* __restrict__ sW22,   // 24: a*4+k2
                                      const f32x2* __restrict__ vB2h2,  // 4
                                      f32x2* __restrict__ racc2)        // 4
{
    #pragma unroll
    for (int k2 = 0; k2 < 4; ++k2) {
        f32x2 acc = vB2h2[k2];
        acc = fma2(splat2(r2[0].x), sW22[0 * 4 + k2], acc);
        acc = fma2(splat2(r2[0].y), sW22[1 * 4 + k2], acc);
        acc = fma2(splat2(r2[1].x), sW22[2 * 4 + k2], acc);
        acc = fma2(splat2(r2[1].y), sW22[3 * 4 + k2], acc);
        acc = fma2(splat2(r2[2].x), sW22[4 * 4 + k2], acc);
        acc = fma2(splat2(r2[2].y), sW22[5 * 4 + k2], acc);
        racc2[k2] = acc;
    }
}

// R13 = R10 WITHOUT the waves_per_eu attribute (which was the sole cause of
// R10's 32-VGPR/90MB-scratch disaster). Half-LDS staging: rows s=0..3 staged
// in LDS (8 KB); rows 4..7 re-read from global in I1 via a staggered,
// pressure-bounded pipeline (g4 issued ~2000 cy early; g5/g6/g7 one per two
// LDS rows; max 3 extra float4 live). Nuclear rows in registers. LDS
// 18.9 -> 10.5 KB: 15 blocks/CU (30 waves/CU theoretical, ~2x R9). Natural
// allocator target at 8 waves/SIMD is 64 VGPR; this structure needs ~52+12.
// Tripwire: WRITE_SIZE in MBs = spill -> path dead, revert to R9.
__global__ __launch_bounds__(128)
void omni_main(
    const float* __restrict__ dists_nuc,   // (B, NE, NA, DF)
    const float* __restrict__ dists_elec,  // (B, NE, NE, DF)
    const float* __restrict__ Y,           // (NA, KD)
    const float* __restrict__ w2,          // (2, 6, KD)
    const float* __restrict__ ws,          // precomputed constants
    float* __restrict__ out)               // (B,)
{
    const int tid  = threadIdx.x;
    const int h    = tid >> 6;          // wave: electrons of spin h
    const int lane = tid & 63;
    const int il   = lane & 15;
    const int jh   = lane >> 4;         // j quarter (j in [8jh, 8jh+8))
    const int ig   = 16 * h + il;       // this lane's electron
    const int b    = blockIdx.x;
    const int sj   = jh >> 1;           // spin of j range
    const bool same = (sj == h);
    const int t32  = same ? 0 : 32;

    __shared__ float4 ebuf[4 * 128];    // [s<4][tid], 8 KB: half the e-rows
    __shared__ float msg[65][KD];       // n=1 table; row 64 = zeros
    __shared__ float part[2];
    if (tid < KD) msg[64][tid] = 0.0f;

    const f32x2* ws2  = (const f32x2*)ws;
    const f32x2* w2p0 = (const f32x2*)w2;          // n=0: a*4+k2
    const f32x2* w2p1 = (const f32x2*)(w2 + 48);   // n=1
    const f32x2* Yp   = (const f32x2*)Y;

    const float* de = dists_elec + (((size_t)b * NE + ig) * NE + 8 * jh) * DF;
    const float* dn = dists_nuc  + (((size_t)b * NE + ig) * NA + 2 * jh) * DF;
    const float4* de4 = (const float4*)de;

    // Nuclear rows: load once, live in registers across both interactions.
    const float4 nr0 = ((const float4*)dn)[0];
    const float4 nr1 = ((const float4*)dn)[1];

    // =================== interaction 0 (no barrier) ===================
    float zr0[KD];
    {
        f32x2 vB1s2[3], vB2h2[4], msel2[4];
        #pragma unroll
        for (int a2 = 0; a2 < 3; ++a2) vB1s2[a2] = ws2[WS_B1S0 / 2 + a2];
        #pragma unroll
        for (int k2 = 0; k2 < 4; ++k2) vB2h2[k2] = ws2[WS_B2H0 / 2 + k2];
        #pragma unroll
        for (int k2 = 0; k2 < 4; ++k2)
            msel2[k2] = same ? ws2[WS_MS0 / 2 + k2] : ws2[WS_MA0 / 2 + k2];

        // factored electron part: z = msel * (S @ W2 + cnt*B2h)
        const int scnt  = ig - 8 * jh;
        const float fcnt = (jh == (ig >> 3)) ? 7.0f : 8.0f;
        f32x2 S2[3] = {splat2(0.f), splat2(0.f), splat2(0.f)};
        #pragma unroll
        for (int s = 0; s < 8; ++s) {
            const float4 e = de4[s];
            if (s < 4) ebuf[s * 128 + tid] = e;      // stage half for n=1
            f32x2 r2[3];
            wnet_r2(e, vB1s2, ws2 + WS_W1S0 / 2, r2);
            const float mf = (s == scnt) ? 0.0f : 1.0f;
            #pragma unroll
            for (int a2 = 0; a2 < 3; ++a2) S2[a2] = fma2(r2[a2], splat2(mf), S2[a2]);
        }
        f32x2 z2[4];
        #pragma unroll
        for (int k2 = 0; k2 < 4; ++k2) {
            f32x2 acc = splat2(fcnt) * vB2h2[k2];
            acc = fma2(splat2(S2[0].x), w2p0[0 * 4 + k2], acc);
            acc = fma2(splat2(S2[0].y), w2p0[1 * 4 + k2], acc);
            acc = fma2(splat2(S2[1].x), w2p0[2 * 4 + k2], acc);
            acc = fma2(splat2(S2[1].y), w2p0[3 * 4 + k2], acc);
            acc = fma2(splat2(S2[2].x), w2p0[4 * 4 + k2], acc);
            acc = fma2(splat2(S2[2].y), w2p0[5 * 4 + k2], acc);
            z2[k2] = acc * msel2[k2];
        }
        // nuclear part (registers)
        {
            f32x2 r2[3], racc2[4];
            wnet_r2(nr0, vB1s2, ws2 + WS_W1S0 / 2, r2);
            proj2(r2, w2p0, vB2h2, racc2);
            #pragma unroll
            for (int k2 = 0; k2 < 4; ++k2)
                z2[k2] = fma2(racc2[k2], Yp[(2 * jh) * 4 + k2], z2[k2]);
            wnet_r2(nr1, vB1s2, ws2 + WS_W1S0 / 2, r2);
            proj2(r2, w2p0, vB2h2, racc2);
            #pragma unroll
            for (int k2 = 0; k2 < 4; ++k2)
                z2[k2] = fma2(racc2[k2], Yp[(2 * jh + 1) * 4 + k2], z2[k2]);
        }
        #pragma unroll
        for (int k2 = 0; k2 < 4; ++k2) {
            float za = z2[k2].x, zb = z2[k2].y;
            za += __shfl_xor(za, 16, 64); za += __shfl_xor(za, 32, 64);
            zb += __shfl_xor(zb, 16, 64); zb += __shfl_xor(zb, 32, 64);
            zr0[2 * k2] = za; zr0[2 * k2 + 1] = zb;
        }
    }

    // Issue first global re-read early: latency hides under linearization,
    // the early-folded zr0 dot, the barrier, and the first LDS rows.
    float4 g4 = de4[4];

    // =================== interaction 1 ===================
    // phase-1 via linearization: ms = Cs + zr0 @ Ms ; ma = Ca + zr0 @ Ma
    {
        f32x2 ms2[4], ma2[4];
        #pragma unroll
        for (int k2 = 0; k2 < 4; ++k2) {
            ms2[k2] = ws2[WS_CS / 2 + k2];
            ma2[k2] = ws2[WS_CA / 2 + k2];
        }
        #pragma unroll
        for (int kp = 0; kp < KD; ++kp) {
            const f32x2 zk = splat2(zr0[kp]);
            #pragma unroll
            for (int k2 = 0; k2 < 4; ++k2) {
                ms2[k2] = fma2(zk, ws2[WS_MS / 2 + kp * 4 + k2], ms2[k2]);
                ma2[k2] = fma2(zk, ws2[WS_MA / 2 + kp * 4 + k2], ma2[k2]);
            }
        }
        if (jh == 0) {
            #pragma unroll
            for (int k2 = 0; k2 < 4; ++k2) *(f32x2*)&msg[ig][2 * k2] = ms2[k2];
        } else if (jh == 2) {
            #pragma unroll
            for (int k2 = 0; k2 < 4; ++k2) *(f32x2*)&msg[32 + ig][2 * k2] = ma2[k2];
        }
    }

    // Fold zr0's orbital contribution NOW: zr0 dies here, freeing 8 VGPRs
    // for the g-pipeline in interaction 1.
    float dot = ws[WS_BASE];
    #pragma unroll
    for (int k = 0; k < KD; ++k) dot = fmaf(zr0[k], ws[WS_GO0 + k], dot);

    __syncthreads();

    float zr1[KD];
    {
        f32x2 vB1s2[3], vB2h2[4];
        #pragma unroll
        for (int a2 = 0; a2 < 3; ++a2) vB1s2[a2] = ws2[WS_B1S1 / 2 + a2];
        #pragma unroll
        for (int k2 = 0; k2 < 4; ++k2) vB2h2[k2] = ws2[WS_B2H1 / 2 + k2];

        f32x2 z2[4] = {splat2(0.f), splat2(0.f), splat2(0.f), splat2(0.f)};

        auto body = [&](const float4 e, const int s) {
            f32x2 r2[3], racc2[4];
            wnet_r2(e, vB1s2, ws2 + WS_W1S1 / 2, r2);
            proj2(r2, w2p1, vB2h2, racc2);
            const int j = 8 * jh + s;
            const int row = (j == ig) ? 64 : (t32 + j);
            const f32x2* mrow = (const f32x2*)&msg[row][0];
            #pragma unroll
            for (int k2 = 0; k2 < 4; ++k2) z2[k2] = fma2(racc2[k2], mrow[k2], z2[k2]);
        };

        // Staggered software pipeline: issue one global re-read per pair of
        // LDS rows; at most 3 g-regs (+12 VGPR) live at once.
        float4 g5 = de4[5];
        body(ebuf[0 * 128 + tid], 0);
        body(ebuf[1 * 128 + tid], 1);
        float4 g6 = de4[6];
        body(ebuf[2 * 128 + tid], 2);
        body(ebuf[3 * 128 + tid], 3);
        body(g4, 4);
        float4 g7 = de4[7];
        body(g5, 5);
        body(g6, 6);
        body(g7, 7);

        // nuclear part (registers, no reload)
        {
            f32x2 r2[3], racc2[4];
            wnet_r2(nr0, vB1s2, ws2 + WS_W1S1 / 2, r2);
            proj2(r2, w2p1, vB2h2, racc2);
            #pragma unroll
            for (int k2 = 0; k2 < 4; ++k2)
                z2[k2] = fma2(racc2[k2], Yp[(2 * jh) * 4 + k2], z2[k2]);
            wnet_r2(nr1, vB1s2, ws2 + WS_W1S1 / 2, r2);
            proj2(r2, w2p1, vB2h2, racc2);
            #pragma unroll
            for (int k2 = 0; k2 < 4; ++k2)
                z2[k2] = fma2(racc2[k2], Yp[(2 * jh + 1) * 4 + k2], z2[k2]);
        }
        #pragma unroll
        for (int k2 = 0; k2 < 4; ++k2) {
            float za = z2[k2].x, zb = z2[k2].y;
            za += __shfl_xor(za, 16, 64); za += __shfl_xor(za, 32, 64);
            zb += __shfl_xor(zb, 16, 64); zb += __shfl_xor(zb, 32, 64);
            zr1[2 * k2] = za; zr1[2 * k2 + 1] = zb;
        }
    }

    // =================== epilogue ===================
    #pragma unroll
    for (int k = 0; k < KD; ++k) dot = fmaf(zr1[k], ws[WS_GO1 + k], dot);
    dot *= 0.25f;    // each electron replicated across 4 lanes
    #pragma unroll
    for (int off = 1; off < 64; off <<= 1) dot += __shfl_xor(dot, off, 64);
    if (lane == 0) part[h] = dot;
    __syncthreads();
    if (tid == 0) out[b] = part[0] + part[1];
}

extern "C" void kernel_launch(void* const* d_in, const int* in_sizes, int n_in,
                              void* d_out, int out_size, void* d_ws, size_t ws_size,
                              hipStream_t stream) {
    const float* dists_nuc  = (const float*)d_in[0];
    const float* dists_elec = (const float*)d_in[1];
    const float* X     = (const float*)d_in[2];
    const float* Y     = (const float*)d_in[3];
    const float* w1    = (const float*)d_in[4];
    const float* wb1   = (const float*)d_in[5];
    const float* w2    = (const float*)d_in[6];
    const float* wb2   = (const float*)d_in[7];
    const float* hs_w  = (const float*)d_in[8];
    const float* hs_b  = (const float*)d_in[9];
    const float* ha_w  = (const float*)d_in[10];
    const float* ha_b  = (const float*)d_in[11];
    const float* g_w   = (const float*)d_in[12];
    const float* g_b   = (const float*)d_in[13];
    const float* orb_w = (const float*)d_in[14];
    float* out = (float*)d_out;
    float* ws  = (float*)d_ws;

    omni_setup<<<1, 256, 0, stream>>>(X, w1, wb1, w2, wb2, hs_w, hs_b,
                                      ha_w, ha_b, g_w, g_b, orb_w, ws);
    omni_main<<<BATCH, 128, 0, stream>>>(dists_nuc, dists_elec, Y, w2, ws, out);
}

// Round 9
// 146.066 us; speedup vs baseline: 1.0419x; 1.0419x over previous
//
#include <hip/hip_runtime.h>

#define NE 32   // electrons
#define NA 8    // atoms
#define DF 4    // dist features
#define KD 8    // kernel dim
#define ED 16   // embedding dim
#define BATCH 4096

// d_ws layout (floats) — all offsets even (f32x2-aligned)
#define WS_W1S0 0     // w1[n=0]*log2e   (d*6+a), 24
#define WS_W1S1 24
#define WS_B1S0 48    // wb1*log2e, 6 each
#define WS_B1S1 54
#define WS_B2H0 60    // wb2*log2e - sum_a w2[a][k], 8 each
#define WS_B2H1 68
#define WS_MS0  76    // n=0 same-spin msg vector, 8
#define WS_MA0  84    // n=0 anti-spin msg vector, 8
#define WS_MS   92    // Ms[kp][k] = (ln2*g_w0) @ hs_w1, 8x8
#define WS_MA   156   // Ma[kp][k] = (ln2*g_w0) @ ha_w1, 8x8
#define WS_CS   220   // (X+g_b0)@hs_w1 + hs_b1, 8
#define WS_CA   228
#define WS_GO0  236   // ln2*g_w0 @ orb, 8
#define WS_GO1  244
#define WS_BASE 252   // (X+g_b0+g_b1)@orb, 1

typedef float f32x2 __attribute__((ext_vector_type(2)));
__device__ __forceinline__ f32x2 splat2(float s) { f32x2 r; r.x = s; r.y = s; return r; }
__device__ __forceinline__ f32x2 fma2(f32x2 a, f32x2 b, f32x2 c) {
    return __builtin_elementwise_fma(a, b, c);
}

__global__ void omni_setup(const float* __restrict__ X,   const float* __restrict__ w1,
                           const float* __restrict__ wb1, const float* __restrict__ w2,
                           const float* __restrict__ wb2, const float* __restrict__ hs_w,
                           const float* __restrict__ hs_b,const float* __restrict__ ha_w,
                           const float* __restrict__ ha_b,const float* __restrict__ g_w,
                           const float* __restrict__ g_b, const float* __restrict__ orb_w,
                           float* __restrict__ ws)
{
    const int t = threadIdx.x;
    const float L   = 1.4426950408889634f;   // log2(e)
    const float LN2 = 0.6931471805599453f;
    if (t < 48) {                                   // W1s, both n
        ws[t] = w1[t] * L;
    } else if (t < 60) {                            // B1s
        ws[t] = wb1[t - 48] * L;
    } else if (t < 76) {                            // B2h
        const int u = t - 60, n = u >> 3, k = u & 7;
        float sw = 0.f;
        for (int a = 0; a < 6; ++a) sw += w2[n * 48 + a * KD + k];
        ws[t] = wb2[n * KD + k] * L - sw;
    } else if (t < 92) {                            // ms0 / ma0
        const int u = t - 76, tab = u >> 3, k = u & 7;
        const float* mw = tab ? ha_w : hs_w;        // n=0 slice
        const float* mb = tab ? ha_b : hs_b;
        float acc = mb[k];
        for (int c = 0; c < ED; ++c) acc += X[c] * mw[c * KD + k];
        ws[t] = acc;
    } else if (t < 220) {                           // Ms / Ma (8x8)
        int u = t - 92; const int tab = u >> 6; u &= 63;
        const int kp = u >> 3, k = u & 7;
        const float* mw = (tab ? ha_w : hs_w) + ED * KD;   // n=1 slice
        float acc = 0.f;
        for (int c = 0; c < ED; ++c)
            acc += LN2 * g_w[kp * ED + c] * mw[c * KD + k]; // g_w n=0 slice
        ws[t] = acc;
    } else if (t < 236) {                           // Cs / Ca
        const int u = t - 220, tab = u >> 3, k = u & 7;
        const float* mw = (tab ? ha_w : hs_w) + ED * KD;
        const float* mb = (tab ? ha_b : hs_b) + KD;
        float acc = mb[k];
        for (int c = 0; c < ED; ++c) acc += (X[c] + g_b[c]) * mw[c * KD + k];
        ws[t] = acc;
    } else if (t < 252) {                           // go0 / go1
        const int u = t - 236, n = u >> 3, k = u & 7;
        float acc = 0.f;
        for (int c = 0; c < ED; ++c)
            acc += LN2 * g_w[n * KD * ED + k * ED + c] * orb_w[c];
        ws[t] = acc;
    } else if (t == 252) {                          // base
        float acc = 0.f;
        for (int c = 0; c < ED; ++c) acc += (X[c] + g_b[c] + g_b[ED + c]) * orb_w[c];
        ws[t] = acc;
    }
}

// trans stage, k-packed: r2[a2] = log2(1 + 2^(e@W1s + B1s)) for unit pair a2
__device__ __forceinline__ void wnet_r2(const float4 e,
                                        const f32x2* __restrict__ vB1s2,  // 3
                                        const f32x2* __restrict__ sW12,   // 12: d*3+a2
                                        f32x2* __restrict__ r2)           // 3
{
    #pragma unroll
    for (int a2 = 0; a2 < 3; ++a2) {
        f32x2 u = fma2(splat2(e.x), sW12[a2], vB1s2[a2]);
        u = fma2(splat2(e.y), sW12[3 + a2], u);
        u = fma2(splat2(e.z), sW12[6 + a2], u);
        u = fma2(splat2(e.w), sW12[9 + a2], u);
        f32x2 t;
        t.x = __builtin_amdgcn_exp2f(u.x);
        t.y = __builtin_amdgcn_exp2f(u.y);
        t = t + splat2(1.0f);
        r2[a2].x = __builtin_amdgcn_logf(t.x);
        r2[a2].y = __builtin_amdgcn_logf(t.y);
    }
}

// projection, k-packed: racc2[k2] = B2h2[k2] + sum_a r[a]*W2[a][k-pair]
__device__ __forceinline__ void proj2(const f32x2* __restrict__ r2,
                                      const f32x2* __restrict__ sW22,   // 24: a*4+k2
                                      const f32x2* __restrict__ vB2h2,  // 4
                                      f32x2* __restrict__ racc2)        // 4
{
    #pragma unroll
    for (int k2 = 0; k2 < 4; ++k2) {
        f32x2 acc = vB2h2[k2];
        acc = fma2(splat2(r2[0].x), sW22[0 * 4 + k2], acc);
        acc = fma2(splat2(r2[0].y), sW22[1 * 4 + k2], acc);
        acc = fma2(splat2(r2[1].x), sW22[2 * 4 + k2], acc);
        acc = fma2(splat2(r2[1].y), sW22[3 * 4 + k2], acc);
        acc = fma2(splat2(r2[2].x), sW22[4 * 4 + k2], acc);
        acc = fma2(splat2(r2[2].y), sW22[5 * 4 + k2], acc);
        racc2[k2] = acc;
    }
}

// R14: ILP-first. Eight rounds showed measured residency is PINNED at
// ~10 waves/CU regardless of the theoretical cap (16/30/32), and each wave
// is ~85% stalled on the fma->exp2->log2 dependent chains. So stop chasing
// occupancy; widen per-wave ILP instead. All 10 distance rows live in
// REGISTERS across both interactions (R1's structure — which failed ONLY
// because the default allocator heuristic targeted 8 waves/EU = 64 VGPR and
// spilled). amdgpu_waves_per_eu(4,4) pins the target: budget 512/4 = 128
// VGPR >= the ~110 this needs, and max=4 forbids squeezing below it (R10's
// (8,8) failure was budget 64 < need). LDS -> 2.5 KB. 10 loads hoisted to
// kernel top = 10 outstanding VMEM/lane. Tripwire: VGPR<=64 or WRITE_SIZE
// in MBs = attribute failed -> revert to R9.
__global__ __launch_bounds__(128)
__attribute__((amdgpu_waves_per_eu(4, 4)))
void omni_main(
    const float* __restrict__ dists_nuc,   // (B, NE, NA, DF)
    const float* __restrict__ dists_elec,  // (B, NE, NE, DF)
    const float* __restrict__ Y,           // (NA, KD)
    const float* __restrict__ w2,          // (2, 6, KD)
    const float* __restrict__ ws,          // precomputed constants
    float* __restrict__ out)               // (B,)
{
    const int tid  = threadIdx.x;
    const int h    = tid >> 6;          // wave: electrons of spin h
    const int lane = tid & 63;
    const int il   = lane & 15;
    const int jh   = lane >> 4;         // j quarter (j in [8jh, 8jh+8))
    const int ig   = 16 * h + il;       // this lane's electron
    const int b    = blockIdx.x;
    const int sj   = jh >> 1;           // spin of j range
    const bool same = (sj == h);
    const int t32  = same ? 0 : 32;

    __shared__ float msg[65][KD];       // n=1 table; row 64 = zeros
    __shared__ float part[2];
    if (tid < KD) msg[64][tid] = 0.0f;

    const f32x2* ws2  = (const f32x2*)ws;
    const f32x2* w2p0 = (const f32x2*)w2;          // n=0: a*4+k2
    const f32x2* w2p1 = (const f32x2*)(w2 + 48);   // n=1
    const f32x2* Yp   = (const f32x2*)Y;

    const float* de = dists_elec + (((size_t)b * NE + ig) * NE + 8 * jh) * DF;
    const float* dn = dists_nuc  + (((size_t)b * NE + ig) * NA + 2 * jh) * DF;

    // Hoist ALL global loads: 10 outstanding dwordx4 per lane. These live in
    // registers across BOTH interactions (40 VGPR — fits the 128 budget).
    float4 er[8];
    float4 nr[2];
    #pragma unroll
    for (int s = 0; s < 8; ++s) er[s] = ((const float4*)de)[s];
    nr[0] = ((const float4*)dn)[0];
    nr[1] = ((const float4*)dn)[1];

    // =================== interaction 0 (no barrier) ===================
    float zr0[KD];
    {
        f32x2 vB1s2[3], vB2h2[4], msel2[4];
        #pragma unroll
        for (int a2 = 0; a2 < 3; ++a2) vB1s2[a2] = ws2[WS_B1S0 / 2 + a2];
        #pragma unroll
        for (int k2 = 0; k2 < 4; ++k2) vB2h2[k2] = ws2[WS_B2H0 / 2 + k2];
        #pragma unroll
        for (int k2 = 0; k2 < 4; ++k2)
            msel2[k2] = same ? ws2[WS_MS0 / 2 + k2] : ws2[WS_MA0 / 2 + k2];

        // factored electron part: z = msel * (S @ W2 + cnt*B2h)
        const int scnt  = ig - 8 * jh;
        const float fcnt = (jh == (ig >> 3)) ? 7.0f : 8.0f;
        f32x2 S2[3] = {splat2(0.f), splat2(0.f), splat2(0.f)};
        #pragma unroll
        for (int s = 0; s < 8; ++s) {
            f32x2 r2[3];
            wnet_r2(er[s], vB1s2, ws2 + WS_W1S0 / 2, r2);
            const float mf = (s == scnt) ? 0.0f : 1.0f;
            #pragma unroll
            for (int a2 = 0; a2 < 3; ++a2) S2[a2] = fma2(r2[a2], splat2(mf), S2[a2]);
        }
        f32x2 z2[4];
        #pragma unroll
        for (int k2 = 0; k2 < 4; ++k2) {
            f32x2 acc = splat2(fcnt) * vB2h2[k2];
            acc = fma2(splat2(S2[0].x), w2p0[0 * 4 + k2], acc);
            acc = fma2(splat2(S2[0].y), w2p0[1 * 4 + k2], acc);
            acc = fma2(splat2(S2[1].x), w2p0[2 * 4 + k2], acc);
            acc = fma2(splat2(S2[1].y), w2p0[3 * 4 + k2], acc);
            acc = fma2(splat2(S2[2].x), w2p0[4 * 4 + k2], acc);
            acc = fma2(splat2(S2[2].y), w2p0[5 * 4 + k2], acc);
            z2[k2] = acc * msel2[k2];
        }
        // nuclear part (registers)
        {
            f32x2 r2[3], racc2[4];
            wnet_r2(nr[0], vB1s2, ws2 + WS_W1S0 / 2, r2);
            proj2(r2, w2p0, vB2h2, racc2);
            #pragma unroll
            for (int k2 = 0; k2 < 4; ++k2)
                z2[k2] = fma2(racc2[k2], Yp[(2 * jh) * 4 + k2], z2[k2]);
            wnet_r2(nr[1], vB1s2, ws2 + WS_W1S0 / 2, r2);
            proj2(r2, w2p0, vB2h2, racc2);
            #pragma unroll
            for (int k2 = 0; k2 < 4; ++k2)
                z2[k2] = fma2(racc2[k2], Yp[(2 * jh + 1) * 4 + k2], z2[k2]);
        }
        #pragma unroll
        for (int k2 = 0; k2 < 4; ++k2) {
            float za = z2[k2].x, zb = z2[k2].y;
            za += __shfl_xor(za, 16, 64); za += __shfl_xor(za, 32, 64);
            zb += __shfl_xor(zb, 16, 64); zb += __shfl_xor(zb, 32, 64);
            zr0[2 * k2] = za; zr0[2 * k2 + 1] = zb;
        }
    }

    // =================== interaction 1 ===================
    // phase-1 via linearization: ms = Cs + zr0 @ Ms ; ma = Ca + zr0 @ Ma
    {
        f32x2 ms2[4], ma2[4];
        #pragma unroll
        for (int k2 = 0; k2 < 4; ++k2) {
            ms2[k2] = ws2[WS_CS / 2 + k2];
            ma2[k2] = ws2[WS_CA / 2 + k2];
        }
        #pragma unroll
        for (int kp = 0; kp < KD; ++kp) {
            const f32x2 zk = splat2(zr0[kp]);
            #pragma unroll
            for (int k2 = 0; k2 < 4; ++k2) {
                ms2[k2] = fma2(zk, ws2[WS_MS / 2 + kp * 4 + k2], ms2[k2]);
                ma2[k2] = fma2(zk, ws2[WS_MA / 2 + kp * 4 + k2], ma2[k2]);
            }
        }
        if (jh == 0) {
            #pragma unroll
            for (int k2 = 0; k2 < 4; ++k2) *(f32x2*)&msg[ig][2 * k2] = ms2[k2];
        } else if (jh == 2) {
            #pragma unroll
            for (int k2 = 0; k2 < 4; ++k2) *(f32x2*)&msg[32 + ig][2 * k2] = ma2[k2];
        }
    }

    // Fold zr0's orbital contribution NOW: zr0 dies here (frees 8 VGPRs).
    float dot = ws[WS_BASE];
    #pragma unroll
    for (int k = 0; k < KD; ++k) dot = fmaf(zr0[k], ws[WS_GO0 + k], dot);

    __syncthreads();

    float zr1[KD];
    {
        f32x2 vB1s2[3], vB2h2[4];
        #pragma unroll
        for (int a2 = 0; a2 < 3; ++a2) vB1s2[a2] = ws2[WS_B1S1 / 2 + a2];
        #pragma unroll
        for (int k2 = 0; k2 < 4; ++k2) vB2h2[k2] = ws2[WS_B2H1 / 2 + k2];

        f32x2 z2[4] = {splat2(0.f), splat2(0.f), splat2(0.f), splat2(0.f)};
        #pragma unroll
        for (int s = 0; s < 8; ++s) {
            f32x2 r2[3], racc2[4];
            wnet_r2(er[s], vB1s2, ws2 + WS_W1S1 / 2, r2);   // registers
            proj2(r2, w2p1, vB2h2, racc2);
            const int j = 8 * jh + s;
            const int row = (j == ig) ? 64 : (t32 + j);
            const f32x2* mrow = (const f32x2*)&msg[row][0];
            #pragma unroll
            for (int k2 = 0; k2 < 4; ++k2) z2[k2] = fma2(racc2[k2], mrow[k2], z2[k2]);
        }
        {
            f32x2 r2[3], racc2[4];
            wnet_r2(nr[0], vB1s2, ws2 + WS_W1S1 / 2, r2);
            proj2(r2, w2p1, vB2h2, racc2);
            #pragma unroll
            for (int k2 = 0; k2 < 4; ++k2)
                z2[k2] = fma2(racc2[k2], Yp[(2 * jh) * 4 + k2], z2[k2]);
            wnet_r2(nr[1], vB1s2, ws2 + WS_W1S1 / 2, r2);
            proj2(r2, w2p1, vB2h2, racc2);
            #pragma unroll
            for (int k2 = 0; k2 < 4; ++k2)
                z2[k2] = fma2(racc2[k2], Yp[(2 * jh + 1) * 4 + k2], z2[k2]);
        }
        #pragma unroll
        for (int k2 = 0; k2 < 4; ++k2) {
            float za = z2[k2].x, zb = z2[k2].y;
            za += __shfl_xor(za, 16, 64); za += __shfl_xor(za, 32, 64);
            zb += __shfl_xor(zb, 16, 64); zb += __shfl_xor(zb, 32, 64);
            zr1[2 * k2] = za; zr1[2 * k2 + 1] = zb;
        }
    }

    // =================== epilogue ===================
    #pragma unroll
    for (int k = 0; k < KD; ++k) dot = fmaf(zr1[k], ws[WS_GO1 + k], dot);
    dot *= 0.25f;    // each electron replicated across 4 lanes
    #pragma unroll
    for (int off = 1; off < 64; off <<= 1) dot += __shfl_xor(dot, off, 64);
    if (lane == 0) part[h] = dot;
    __syncthreads();
    if (tid == 0) out[b] = part[0] + part[1];
}

extern "C" void kernel_launch(void* const* d_in, const int* in_sizes, int n_in,
                              void* d_out, int out_size, void* d_ws, size_t ws_size,
                              hipStream_t stream) {
    const float* dists_nuc  = (const float*)d_in[0];
    const float* dists_elec = (const float*)d_in[1];
    const float* X     = (const float*)d_in[2];
    const float* Y     = (const float*)d_in[3];
    const float* w1    = (const float*)d_in[4];
    const float* wb1   = (const float*)d_in[5];
    const float* w2    = (const float*)d_in[6];
    const float* wb2   = (const float*)d_in[7];
    const float* hs_w  = (const float*)d_in[8];
    const float* hs_b  = (const float*)d_in[9];
    const float* ha_w  = (const float*)d_in[10];
    const float* ha_b  = (const float*)d_in[11];
    const float* g_w   = (const float*)d_in[12];
    const float* g_b   = (const float*)d_in[13];
    const float* orb_w = (const float*)d_in[14];
    float* out = (float*)d_out;
    float* ws  = (float*)d_ws;

    omni_setup<<<1, 256, 0, stream>>>(X, w1, wb1, w2, wb2, hs_w, hs_b,
                                      ha_w, ha_b, g_w, g_b, orb_w, ws);
    omni_main<<<BATCH, 128, 0, stream>>>(dists_nuc, dists_elec, Y, w2, ws, out);
}

// Round 10
// 144.911 us; speedup vs baseline: 1.0502x; 1.0080x over previous
//
#include <hip/hip_runtime.h>

#define NE 32   // electrons
#define NA 8    // atoms
#define DF 4    // dist features
#define KD 8    // kernel dim
#define ED 16   // embedding dim
#define BATCH 4096

// d_ws layout (floats) — all offsets even (f32x2-aligned)
#define WS_W1S0 0     // w1[n=0]*log2e   (d*6+a), 24
#define WS_W1S1 24
#define WS_B1S0 48    // wb1*log2e, 6 each
#define WS_B1S1 54
#define WS_B2H0 60    // wb2*log2e - sum_a w2[a][k], 8 each
#define WS_B2H1 68
#define WS_MS0  76    // n=0 same-spin msg vector, 8
#define WS_MA0  84    // n=0 anti-spin msg vector, 8
#define WS_MS   92    // Ms[kp][k] = (ln2*g_w0) @ hs_w1, 8x8
#define WS_MA   156   // Ma[kp][k] = (ln2*g_w0) @ ha_w1, 8x8
#define WS_CS   220   // (X+g_b0)@hs_w1 + hs_b1, 8
#define WS_CA   228
#define WS_GO0  236   // ln2*g_w0 @ orb, 8
#define WS_GO1  244
#define WS_BASE 252   // (X+g_b0+g_b1)@orb, 1

typedef float f32x2 __attribute__((ext_vector_type(2)));
__device__ __forceinline__ f32x2 splat2(float s) { f32x2 r; r.x = s; r.y = s; return r; }
__device__ __forceinline__ f32x2 fma2(f32x2 a, f32x2 b, f32x2 c) {
    return __builtin_elementwise_fma(a, b, c);
}

__global__ void omni_setup(const float* __restrict__ X,   const float* __restrict__ w1,
                           const float* __restrict__ wb1, const float* __restrict__ w2,
                           const float* __restrict__ wb2, const float* __restrict__ hs_w,
                           const float* __restrict__ hs_b,const float* __restrict__ ha_w,
                           const float* __restrict__ ha_b,const float* __restrict__ g_w,
                           const float* __restrict__ g_b, const float* __restrict__ orb_w,
                           float* __restrict__ ws)
{
    const int t = threadIdx.x;
    const float L   = 1.4426950408889634f;   // log2(e)
    const float LN2 = 0.6931471805599453f;
    if (t < 48) {                                   // W1s, both n
        ws[t] = w1[t] * L;
    } else if (t < 60) {                            // B1s
        ws[t] = wb1[t - 48] * L;
    } else if (t < 76) {                            // B2h
        const int u = t - 60, n = u >> 3, k = u & 7;
        float sw = 0.f;
        for (int a = 0; a < 6; ++a) sw += w2[n * 48 + a * KD + k];
        ws[t] = wb2[n * KD + k] * L - sw;
    } else if (t < 92) {                            // ms0 / ma0
        const int u = t - 76, tab = u >> 3, k = u & 7;
        const float* mw = tab ? ha_w : hs_w;        // n=0 slice
        const float* mb = tab ? ha_b : hs_b;
        float acc = mb[k];
        for (int c = 0; c < ED; ++c) acc += X[c] * mw[c * KD + k];
        ws[t] = acc;
    } else if (t < 220) {                           // Ms / Ma (8x8)
        int u = t - 92; const int tab = u >> 6; u &= 63;
        const int kp = u >> 3, k = u & 7;
        const float* mw = (tab ? ha_w : hs_w) + ED * KD;   // n=1 slice
        float acc = 0.f;
        for (int c = 0; c < ED; ++c)
            acc += LN2 * g_w[kp * ED + c] * mw[c * KD + k]; // g_w n=0 slice
        ws[t] = acc;
    } else if (t < 236) {                           // Cs / Ca
        const int u = t - 220, tab = u >> 3, k = u & 7;
        const float* mw = (tab ? ha_w : hs_w) + ED * KD;
        const float* mb = (tab ? ha_b : hs_b) + KD;
        float acc = mb[k];
        for (int c = 0; c < ED; ++c) acc += (X[c] + g_b[c]) * mw[c * KD + k];
        ws[t] = acc;
    } else if (t < 252) {                           // go0 / go1
        const int u = t - 236, n = u >> 3, k = u & 7;
        float acc = 0.f;
        for (int c = 0; c < ED; ++c)
            acc += LN2 * g_w[n * KD * ED + k * ED + c] * orb_w[c];
        ws[t] = acc;
    } else if (t == 252) {                          // base
        float acc = 0.f;
        for (int c = 0; c < ED; ++c) acc += (X[c] + g_b[c] + g_b[ED + c]) * orb_w[c];
        ws[t] = acc;
    }
}

// trans stage, k-packed: r2[a2] = log2(1 + 2^(e@W1s + B1s)) for unit pair a2
__device__ __forceinline__ void wnet_r2(const float4 e,
                                        const f32x2* __restrict__ vB1s2,  // 3
                                        const f32x2* __restrict__ sW12,   // 12: d*3+a2
                                        f32x2* __restrict__ r2)           // 3
{
    #pragma unroll
    for (int a2 = 0; a2 < 3; ++a2) {
        f32x2 u = fma2(splat2(e.x), sW12[a2], vB1s2[a2]);
        u = fma2(splat2(e.y), sW12[3 + a2], u);
        u = fma2(splat2(e.z), sW12[6 + a2], u);
        u = fma2(splat2(e.w), sW12[9 + a2], u);
        f32x2 t;
        t.x = __builtin_amdgcn_exp2f(u.x);
        t.y = __builtin_amdgcn_exp2f(u.y);
        t = t + splat2(1.0f);
        r2[a2].x = __builtin_amdgcn_logf(t.x);
        r2[a2].y = __builtin_amdgcn_logf(t.y);
    }
}

// projection, k-packed: racc2[k2] = B2h2[k2] + sum_a r[a]*W2[a][k-pair]
__device__ __forceinline__ void proj2(const f32x2* __restrict__ r2,
                                      const f32x2* __restrict__ sW22,   // 24: a*4+k2
                                      const f32x2* __restrict__ vB2h2,  // 4
                                      f32x2* __restrict__ racc2)        // 4
{
    #pragma unroll
    for (int k2 = 0; k2 < 4; ++k2) {
        f32x2 acc = vB2h2[k2];
        acc = fma2(splat2(r2[0].x), sW22[0 * 4 + k2], acc);
        acc = fma2(splat2(r2[0].y), sW22[1 * 4 + k2], acc);
        acc = fma2(splat2(r2[1].x), sW22[2 * 4 + k2], acc);
        acc = fma2(splat2(r2[1].y), sW22[3 * 4 + k2], acc);
        acc = fma2(splat2(r2[2].x), sW22[4 * 4 + k2], acc);
        acc = fma2(splat2(r2[2].y), sW22[5 * 4 + k2], acc);
        racc2[k2] = acc;
    }
}

// R15: wnet-n1 HOISTED into interaction 0. The n=1 MLP over the distance
// rows does NOT depend on the barrier (only the msg multiply does), so both
// interactions' MLPs for the same row are computed back-to-back: two
// independent fma->exp2->log2 chains in flight per row (2x chain ILP), and
// interaction 1 collapses to 40 packed FMAs + reductions. Saves ~10x
// (12 trans + 27 pk) ~ 1500 cy/wave (~35% of issue). Carried state: racc
// (10 rows x 8 floats = 80 VGPR) replaces er/nr (40 VGPR) after I0.
// waves_per_eu(3,4): budget 512/3=170 >= peak ~125, min 3 waves/SIMD = 12
// waves/CU = the measured residency anyway (pinned ~10 across 9 rounds).
// Tripwire: WRITE_SIZE in MBs = spill -> revert.
__global__ __launch_bounds__(128)
__attribute__((amdgpu_waves_per_eu(3, 4)))
void omni_main(
    const float* __restrict__ dists_nuc,   // (B, NE, NA, DF)
    const float* __restrict__ dists_elec,  // (B, NE, NE, DF)
    const float* __restrict__ Y,           // (NA, KD)
    const float* __restrict__ w2,          // (2, 6, KD)
    const float* __restrict__ ws,          // precomputed constants
    float* __restrict__ out)               // (B,)
{
    const int tid  = threadIdx.x;
    const int h    = tid >> 6;          // wave: electrons of spin h
    const int lane = tid & 63;
    const int il   = lane & 15;
    const int jh   = lane >> 4;         // j quarter (j in [8jh, 8jh+8))
    const int ig   = 16 * h + il;       // this lane's electron
    const int b    = blockIdx.x;
    const int sj   = jh >> 1;           // spin of j range
    const bool same = (sj == h);
    const int t32  = same ? 0 : 32;

    __shared__ float msg[65][KD];       // n=1 table; row 64 = zeros
    __shared__ float part[2];
    if (tid < KD) msg[64][tid] = 0.0f;

    const f32x2* ws2  = (const f32x2*)ws;
    const f32x2* w2p0 = (const f32x2*)w2;          // n=0: a*4+k2
    const f32x2* w2p1 = (const f32x2*)(w2 + 48);   // n=1
    const f32x2* Yp   = (const f32x2*)Y;

    const float* de = dists_elec + (((size_t)b * NE + ig) * NE + 8 * jh) * DF;
    const float* dn = dists_nuc  + (((size_t)b * NE + ig) * NA + 2 * jh) * DF;

    // Hoist all 10 global loads (10 outstanding VMEM/lane).
    float4 er[8];
    float4 nr[2];
    #pragma unroll
    for (int s = 0; s < 8; ++s) er[s] = ((const float4*)de)[s];
    nr[0] = ((const float4*)dn)[0];
    nr[1] = ((const float4*)dn)[1];

    // n=1 projections, computed in I0, consumed in I1 (10 rows x 4 f32x2).
    f32x2 racc1[40];

    // =================== interaction 0 (+ hoisted n=1 MLP) ===================
    float zr0[KD];
    {
        f32x2 vB1s0[3], vB1s1[3], vB2h0[4], vB2h1[4], msel2[4];
        #pragma unroll
        for (int a2 = 0; a2 < 3; ++a2) {
            vB1s0[a2] = ws2[WS_B1S0 / 2 + a2];
            vB1s1[a2] = ws2[WS_B1S1 / 2 + a2];
        }
        #pragma unroll
        for (int k2 = 0; k2 < 4; ++k2) {
            vB2h0[k2] = ws2[WS_B2H0 / 2 + k2];
            vB2h1[k2] = ws2[WS_B2H1 / 2 + k2];
            msel2[k2] = same ? ws2[WS_MS0 / 2 + k2] : ws2[WS_MA0 / 2 + k2];
        }

        // factored electron part: z = msel * (S @ W2 + cnt*B2h)
        const int scnt  = ig - 8 * jh;
        const float fcnt = (jh == (ig >> 3)) ? 7.0f : 8.0f;
        f32x2 S2[3] = {splat2(0.f), splat2(0.f), splat2(0.f)};
        #pragma unroll
        for (int s = 0; s < 8; ++s) {
            // n=0 and n=1 chains for the same row: independent, co-scheduled.
            f32x2 r0[3], r1[3];
            wnet_r2(er[s], vB1s0, ws2 + WS_W1S0 / 2, r0);
            wnet_r2(er[s], vB1s1, ws2 + WS_W1S1 / 2, r1);
            const float mf = (s == scnt) ? 0.0f : 1.0f;
            #pragma unroll
            for (int a2 = 0; a2 < 3; ++a2) S2[a2] = fma2(r0[a2], splat2(mf), S2[a2]);
            proj2(r1, w2p1, vB2h1, &racc1[s * 4]);
        }
        f32x2 z2[4];
        #pragma unroll
        for (int k2 = 0; k2 < 4; ++k2) {
            f32x2 acc = splat2(fcnt) * vB2h0[k2];
            acc = fma2(splat2(S2[0].x), w2p0[0 * 4 + k2], acc);
            acc = fma2(splat2(S2[0].y), w2p0[1 * 4 + k2], acc);
            acc = fma2(splat2(S2[1].x), w2p0[2 * 4 + k2], acc);
            acc = fma2(splat2(S2[1].y), w2p0[3 * 4 + k2], acc);
            acc = fma2(splat2(S2[2].x), w2p0[4 * 4 + k2], acc);
            acc = fma2(splat2(S2[2].y), w2p0[5 * 4 + k2], acc);
            z2[k2] = acc * msel2[k2];
        }
        // nuclear part: n=0 accumulate now, n=1 projection carried.
        #pragma unroll
        for (int t = 0; t < 2; ++t) {
            f32x2 r0[3], r1[3], racc0[4];
            wnet_r2(nr[t], vB1s0, ws2 + WS_W1S0 / 2, r0);
            wnet_r2(nr[t], vB1s1, ws2 + WS_W1S1 / 2, r1);
            proj2(r0, w2p0, vB2h0, racc0);
            proj2(r1, w2p1, vB2h1, &racc1[(8 + t) * 4]);
            #pragma unroll
            for (int k2 = 0; k2 < 4; ++k2)
                z2[k2] = fma2(racc0[k2], Yp[(2 * jh + t) * 4 + k2], z2[k2]);
        }
        #pragma unroll
        for (int k2 = 0; k2 < 4; ++k2) {
            float za = z2[k2].x, zb = z2[k2].y;
            za += __shfl_xor(za, 16, 64); za += __shfl_xor(za, 32, 64);
            zb += __shfl_xor(zb, 16, 64); zb += __shfl_xor(zb, 32, 64);
            zr0[2 * k2] = za; zr0[2 * k2 + 1] = zb;
        }
    }

    // =================== interaction 1 ===================
    // phase-1 via linearization: ms = Cs + zr0 @ Ms ; ma = Ca + zr0 @ Ma
    {
        f32x2 ms2[4], ma2[4];
        #pragma unroll
        for (int k2 = 0; k2 < 4; ++k2) {
            ms2[k2] = ws2[WS_CS / 2 + k2];
            ma2[k2] = ws2[WS_CA / 2 + k2];
        }
        #pragma unroll
        for (int kp = 0; kp < KD; ++kp) {
            const f32x2 zk = splat2(zr0[kp]);
            #pragma unroll
            for (int k2 = 0; k2 < 4; ++k2) {
                ms2[k2] = fma2(zk, ws2[WS_MS / 2 + kp * 4 + k2], ms2[k2]);
                ma2[k2] = fma2(zk, ws2[WS_MA / 2 + kp * 4 + k2], ma2[k2]);
            }
        }
        if (jh == 0) {
            #pragma unroll
            for (int k2 = 0; k2 < 4; ++k2) *(f32x2*)&msg[ig][2 * k2] = ms2[k2];
        } else if (jh == 2) {
            #pragma unroll
            for (int k2 = 0; k2 < 4; ++k2) *(f32x2*)&msg[32 + ig][2 * k2] = ma2[k2];
        }
    }

    // Fold zr0's orbital contribution now (zr0 dies here).
    float dot = ws[WS_BASE];
    #pragma unroll
    for (int k = 0; k < KD; ++k) dot = fmaf(zr0[k], ws[WS_GO0 + k], dot);

    __syncthreads();

    // I1 compute: pure packed-FMA over the carried racc1 — no MLP here.
    float zr1[KD];
    {
        f32x2 z2[4] = {splat2(0.f), splat2(0.f), splat2(0.f), splat2(0.f)};
        #pragma unroll
        for (int s = 0; s < 8; ++s) {
            const int j = 8 * jh + s;
            const int row = (j == ig) ? 64 : (t32 + j);
            const f32x2* mrow = (const f32x2*)&msg[row][0];
            #pragma unroll
            for (int k2 = 0; k2 < 4; ++k2)
                z2[k2] = fma2(racc1[s * 4 + k2], mrow[k2], z2[k2]);
        }
        #pragma unroll
        for (int t = 0; t < 2; ++t) {
            #pragma unroll
            for (int k2 = 0; k2 < 4; ++k2)
                z2[k2] = fma2(racc1[(8 + t) * 4 + k2], Yp[(2 * jh + t) * 4 + k2], z2[k2]);
        }
        #pragma unroll
        for (int k2 = 0; k2 < 4; ++k2) {
            float za = z2[k2].x, zb = z2[k2].y;
            za += __shfl_xor(za, 16, 64); za += __shfl_xor(za, 32, 64);
            zb += __shfl_xor(zb, 16, 64); zb += __shfl_xor(zb, 32, 64);
            zr1[2 * k2] = za; zr1[2 * k2 + 1] = zb;
        }
    }

    // =================== epilogue ===================
    #pragma unroll
    for (int k = 0; k < KD; ++k) dot = fmaf(zr1[k], ws[WS_GO1 + k], dot);
    dot *= 0.25f;    // each electron replicated across 4 lanes
    #pragma unroll
    for (int off = 1; off < 64; off <<= 1) dot += __shfl_xor(dot, off, 64);
    if (lane == 0) part[h] = dot;
    __syncthreads();
    if (tid == 0) out[b] = part[0] + part[1];
}

extern "C" void kernel_launch(void* const* d_in, const int* in_sizes, int n_in,
                              void* d_out, int out_size, void* d_ws, size_t ws_size,
                              hipStream_t stream) {
    const float* dists_nuc  = (const float*)d_in[0];
    const float* dists_elec = (const float*)d_in[1];
    const float* X     = (const float*)d_in[2];
    const float* Y     = (const float*)d_in[3];
    const float* w1    = (const float*)d_in[4];
    const float* wb1   = (const float*)d_in[5];
    const float* w2    = (const float*)d_in[6];
    const float* wb2   = (const float*)d_in[7];
    const float* hs_w  = (const float*)d_in[8];
    const float* hs_b  = (const float*)d_in[9];
    const float* ha_w  = (const float*)d_in[10];
    const float* ha_b  = (const float*)d_in[11];
    const float* g_w   = (const float*)d_in[12];
    const float* g_b   = (const float*)d_in[13];
    const float* orb_w = (const float*)d_in[14];
    float* out = (float*)d_out;
    float* ws  = (float*)d_ws;

    omni_setup<<<1, 256, 0, stream>>>(X, w1, wb1, w2, wb2, hs_w, hs_b,
                                      ha_w, ha_b, g_w, g_b, orb_w, ws);
    omni_main<<<BATCH, 128, 0, stream>>>(dists_nuc, dists_elec, Y, w2, ws, out);
}